// Round 8
// baseline (128.615 us; speedup 1.0000x reference)
//
#include <hip/hip_runtime.h>

#define T_STEPS 345
#define B_SZ    128
#define IN_SZ   13
#define H_SZ    128
#define OUT_SZ  9
#define XPITCH  16
#define TPAD    384                 // padded t-extent (6*64) for cur2 [t][bo]
#define NBO     (B_SZ * OUT_SZ)     // 1152
#define NCHUNK  22                  // 22*16 = 352 >= 345
#define MASK_BYTES (B_SZ * T_STEPS * 2 * 8)   // 706560, u64 [B][T][2]

// ---------------- K1: layer-1 scan, one thread per hidden neuron ----------------
// BIT-IDENTICAL FP chains to R1/R4/R6 (knife-edge numerics — do not reorder).
__global__ __launch_bounds__(128, 1)
void k1_spikes(const float* __restrict__ x, const float* __restrict__ W1,
               const float* __restrict__ b1, const float* __restrict__ beta1p,
               const float* __restrict__ thr1p,
               unsigned long long* __restrict__ masks)
{
    const int b   = blockIdx.x;
    const int tid = threadIdx.x;    // 0..127 == neuron h

    __shared__ float xst[(T_STEPS + 3) * XPITCH];

    const float* xb = x + (size_t)b * (IN_SZ * T_STEPS);
    for (int i = tid; i < IN_SZ * T_STEPS; i += 128) {
        const int c = i / T_STEPS;
        const int t = i - c * T_STEPS;
        xst[t * XPITCH + c] = xb[i];
    }

    const float bt1 = fminf(fmaxf(beta1p[0], 0.0f), 1.0f);
    const float th1 = thr1p[0];

    float w1r[IN_SZ];
#pragma unroll
    for (int c = 0; c < IN_SZ; ++c) w1r[c] = W1[tid * IN_SZ + c];
    const float b1r = b1[tid];

    float mem1 = 0.0f;
    unsigned long long* mp = masks + (size_t)b * (T_STEPS * 2) + (tid >> 6);
    const bool store_lane = (tid & 63) == 0;

    __syncthreads();

    const float4* xq = (const float4*)xst;
    float4 a0 = xq[0], a1 = xq[1], a2 = xq[2]; float a3 = xst[12];
    float4 c0 = xq[4], c1 = xq[5], c2 = xq[6]; float c3 = xst[XPITCH + 12];

    int t = 0;
    for (; t < T_STEPS - 1; t += 2) {
        const float xa[IN_SZ] = { a0.x,a0.y,a0.z,a0.w, a1.x,a1.y,a1.z,a1.w,
                                  a2.x,a2.y,a2.z,a2.w, a3 };
        const float xc[IN_SZ] = { c0.x,c0.y,c0.z,c0.w, c1.x,c1.y,c1.z,c1.w,
                                  c2.x,c2.y,c2.z,c2.w, c3 };
        a0 = xq[(t+2)*4+0]; a1 = xq[(t+2)*4+1]; a2 = xq[(t+2)*4+2]; a3 = xst[(t+2)*XPITCH+12];
        c0 = xq[(t+3)*4+0]; c1 = xq[(t+3)*4+1]; c2 = xq[(t+3)*4+2]; c3 = xst[(t+3)*XPITCH+12];

        float cura = b1r, curb = b1r;
#pragma unroll
        for (int c = 0; c < IN_SZ; ++c) {
            cura = fmaf(xa[c], w1r[c], cura);
            curb = fmaf(xc[c], w1r[c], curb);
        }

        mem1 = fmaf(bt1, mem1, cura);
        const bool pa = mem1 > th1;
        const unsigned long long ma = __ballot(pa);
        mem1 = fmaf(pa ? -1.0f : 0.0f, th1, mem1);
        if (store_lane) mp[0] = ma;

        mem1 = fmaf(bt1, mem1, curb);
        const bool pb = mem1 > th1;
        const unsigned long long mb = __ballot(pb);
        mem1 = fmaf(pb ? -1.0f : 0.0f, th1, mem1);
        if (store_lane) mp[2] = mb;

        mp += 4;
    }
    {
        const float xa[IN_SZ] = { a0.x,a0.y,a0.z,a0.w, a1.x,a1.y,a1.z,a1.w,
                                  a2.x,a2.y,a2.z,a2.w, a3 };
        float cura = b1r;
#pragma unroll
        for (int c = 0; c < IN_SZ; ++c) cura = fmaf(xa[c], w1r[c], cura);
        mem1 = fmaf(bt1, mem1, cura);
        const bool pa = mem1 > th1;
        const unsigned long long ma = __ballot(pa);
        if (store_lane) mp[0] = ma;
    }
}

// ---------------- K2: cur2 GEMM, bit-masked dot, fully parallel ----------------
// Output layout now [t][bo] so K3's reads coalesce. K2's writes scatter
// (stride 4608 B across lanes) — absorbed by 6912 parallel waves.
__global__ __launch_bounds__(256, 1)
void k2_gemm(const unsigned long long* __restrict__ masks,
             const float* __restrict__ W2, const float* __restrict__ b2,
             float* __restrict__ cur2)
{
    const int gw   = blockIdx.x * 4 + (threadIdx.x >> 6);  // global wave 0..6911
    const int lane = threadIdx.x & 63;
    const int bo   = gw / 6;             // 0..1151
    const int w    = gw - bo * 6;
    const int b    = bo / 9;
    const int o    = bo - b * 9;
    const int t    = w * 64 + lane;      // 0..383
    const int tc   = (t < T_STEPS) ? t : (T_STEPS - 1);   // clamp load addr

    const uint4 mm = *(const uint4*)((const char*)masks +
                                     ((size_t)b * T_STEPS + tc) * 16);

    const float* __restrict__ w2row = W2 + o * H_SZ;
    float acc = 0.0f;
#pragma unroll
    for (int h = 0; h < 32; ++h)
        acc = fmaf((float)((mm.x >> h) & 1u), w2row[h], acc);
#pragma unroll
    for (int h = 0; h < 32; ++h)
        acc = fmaf((float)((mm.y >> h) & 1u), w2row[32 + h], acc);
#pragma unroll
    for (int h = 0; h < 32; ++h)
        acc = fmaf((float)((mm.z >> h) & 1u), w2row[64 + h], acc);
#pragma unroll
    for (int h = 0; h < 32; ++h)
        acc = fmaf((float)((mm.w >> h) & 1u), w2row[96 + h], acc);

    cur2[(size_t)t * NBO + bo] = acc + b2[o];
}

// ---------------- K3: mem2 scan, one lane per (b,o) ----------------
// Chunked 16 steps: coalesced [t][bo] loads double-buffered one chunk ahead;
// outputs buffered in per-parity register arrays then burst-stored, so the
// store-source register overwrite hazard (vmcnt stall) occurs once per chunk
// instead of once per step. Scan arithmetic identical to R7.
__global__ __launch_bounds__(64, 1)
void k3_scan2(const float* __restrict__ cur2, const float* __restrict__ beta2p,
              const float* __restrict__ thr2p, float* __restrict__ out)
{
    const int lid = blockIdx.x * 64 + threadIdx.x;   // 0..1151 == b*9+o
    const float bt2 = fminf(fmaxf(beta2p[0], 0.0f), 1.0f);
    const float th2 = thr2p[0];

    const float* __restrict__ src = cur2 + lid;                 // [t][NBO]
    float* __restrict__ out_spk = out + lid;
    float* __restrict__ out_mem = out + (size_t)T_STEPS * NBO + lid;

    float mem2 = 0.0f;

    float A[16], Bb[16];
#pragma unroll
    for (int j = 0; j < 16; ++j) A[j]  = src[(size_t)j * NBO];
#pragma unroll
    for (int j = 0; j < 16; ++j) Bb[j] = src[(size_t)(16 + j) * NBO];

    float sE[16], mE[16], sO[16], mO[16];

    for (int c = 0; c < NCHUNK; c += 2) {
        // ---- even chunk c: consume A ----
#pragma unroll
        for (int j = 0; j < 16; ++j) {
            mem2 = fmaf(bt2, mem2, A[j]);
            const float sp = (mem2 > th2) ? 1.0f : 0.0f;
            mem2 = fmaf(-sp, th2, mem2);
            sE[j] = sp; mE[j] = mem2;
        }
        const int cn = (c + 2 < NCHUNK) ? (c + 2) : c;   // clamp (redundant reload ok)
#pragma unroll
        for (int j = 0; j < 16; ++j) A[j] = src[(size_t)(cn * 16 + j) * NBO];
        {
            const size_t base = (size_t)c * 16 * NBO;    // even c <= 20 -> all t < 336 in range
#pragma unroll
            for (int j = 0; j < 16; ++j) {
                out_spk[base + (size_t)j * NBO] = sE[j];
                out_mem[base + (size_t)j * NBO] = mE[j];
            }
        }

        // ---- odd chunk c+1: consume Bb ----
#pragma unroll
        for (int j = 0; j < 16; ++j) {
            mem2 = fmaf(bt2, mem2, Bb[j]);
            const float sp = (mem2 > th2) ? 1.0f : 0.0f;
            mem2 = fmaf(-sp, th2, mem2);
            sO[j] = sp; mO[j] = mem2;
        }
        const int cn2 = (c + 3 < NCHUNK) ? (c + 3) : c;
#pragma unroll
        for (int j = 0; j < 16; ++j) Bb[j] = src[(size_t)(cn2 * 16 + j) * NBO];
        if (c + 1 < NCHUNK - 1) {
            const size_t base = (size_t)(c + 1) * 16 * NBO;
#pragma unroll
            for (int j = 0; j < 16; ++j) {
                out_spk[base + (size_t)j * NBO] = sO[j];
                out_mem[base + (size_t)j * NBO] = mO[j];
            }
        } else {
            // chunk 21: t = 336..351, only t < 345 stored (mem2 pollution
            // from padded t >= 345 happens after the last store — harmless)
            const size_t base = (size_t)(c + 1) * 16 * NBO;
#pragma unroll
            for (int j = 0; j < 9; ++j) {
                out_spk[base + (size_t)j * NBO] = sO[j];
                out_mem[base + (size_t)j * NBO] = mO[j];
            }
        }
    }
}

extern "C" void kernel_launch(void* const* d_in, const int* in_sizes, int n_in,
                              void* d_out, int out_size, void* d_ws, size_t ws_size,
                              hipStream_t stream) {
    const float* x     = (const float*)d_in[0];
    const float* W1    = (const float*)d_in[1];
    const float* b1    = (const float*)d_in[2];
    const float* W2    = (const float*)d_in[3];
    const float* b2    = (const float*)d_in[4];
    const float* beta1 = (const float*)d_in[5];
    const float* thr1  = (const float*)d_in[6];
    const float* beta2 = (const float*)d_in[7];
    const float* thr2  = (const float*)d_in[8];
    float* out = (float*)d_out;

    char* ws = (char*)d_ws;
    unsigned long long* masks = (unsigned long long*)ws;        // 706,560 B
    float* cur2 = (float*)(ws + MASK_BYTES);                    // [TPAD][NBO] = 1,769,472 B

    k1_spikes<<<dim3(B_SZ), dim3(128), 0, stream>>>(x, W1, b1, beta1, thr1, masks);
    k2_gemm  <<<dim3(1728), dim3(256), 0, stream>>>(masks, W2, b2, cur2);
    k3_scan2 <<<dim3(NBO / 64), dim3(64), 0, stream>>>(cur2, beta2, thr2, out);
}